// Round 19
// baseline (247.004 us; speedup 1.0000x reference)
//
#include <hip/hip_runtime.h>
#include <hip/hip_bf16.h>

typedef unsigned short u16;
typedef unsigned int u32;
typedef unsigned long long u64;
typedef __attribute__((ext_vector_type(8))) short s16x8;
typedef __attribute__((ext_vector_type(4))) short s16x4;
typedef __attribute__((ext_vector_type(8))) unsigned short u16x8;
typedef __attribute__((ext_vector_type(4))) unsigned short u16x4;
typedef __attribute__((ext_vector_type(4))) float fx4;
typedef __attribute__((ext_vector_type(4))) unsigned int ux4;
typedef __attribute__((ext_vector_type(2))) unsigned int ux2;

__device__ __forceinline__ float bf2f(u16 u){ u32 x=((u32)u)<<16; return __builtin_bit_cast(float,x); }
__device__ __forceinline__ u16 f2bf(float f){ u32 x=__builtin_bit_cast(u32,f); return (u16)((x + 0x7FFFu + ((x>>16)&1u))>>16); }
// packed f32x2 -> bf16x2 (RNE), single HW instr
__device__ __forceinline__ u32 cvtpk(float lo, float hi){
  u32 r; asm("v_cvt_pk_bf16_f32 %0, %1, %2" : "=v"(r) : "v"(lo), "v"(hi)); return r;
}

__device__ __forceinline__ s16x8 ld_bf8(const u16* p){
  s16x4 lo = *(const s16x4*)p;
  s16x4 hi = *(const s16x4*)(p+4);
  s16x8 r;
  r[0]=lo[0]; r[1]=lo[1]; r[2]=lo[2]; r[3]=lo[3];
  r[4]=hi[0]; r[5]=hi[1]; r[6]=hi[2]; r[7]=hi[3];
  return r;
}

// async global->LDS, 16B per lane; LDS dest must be wave-uniform base + lane*16
__device__ __forceinline__ void gload16(const void* g, void* l){
  __builtin_amdgcn_global_load_lds((__attribute__((address_space(1))) void*)g,
                                   (__attribute__((address_space(3))) void*)l, 16, 0, 0);
}

__device__ __forceinline__ u64 spread3(u32 v){
  u64 x = v & 0xFFFFull;
  x = (x | (x<<32)) & 0x001f00000000ffffull;
  x = (x | (x<<16)) & 0x001f0000ff0000ffull;
  x = (x | (x<<8))  & 0x100f00f00f00f00full;
  x = (x | (x<<4))  & 0x10c30c30c30c30c3ull;
  x = (x | (x<<2))  & 0x1249249249249249ull;
  return x;
}

// ---------------- sort stage 0: per-block per-axis min (no atomics, no memset) ----------------
__global__ __launch_bounds__(256) void min3_kernel(const float* __restrict__ xyz, float* __restrict__ minsW, int N)
{
  __shared__ float red[3][4];
  int i = blockIdx.x*256 + threadIdx.x;
  int lane = threadIdx.x&63, wv = threadIdx.x>>6;
  float v0 = xyz[i], v1 = xyz[N+i], v2 = xyz[2*N+i];
  #pragma unroll
  for (int s=1;s<64;s<<=1){
    v0 = fminf(v0, __shfl_xor(v0,s));
    v1 = fminf(v1, __shfl_xor(v1,s));
    v2 = fminf(v2, __shfl_xor(v2,s));
  }
  if (lane==0){ red[0][wv]=v0; red[1][wv]=v1; red[2][wv]=v2; }
  __syncthreads();
  if (threadIdx.x < 3){
    float m = fminf(fminf(red[threadIdx.x][0],red[threadIdx.x][1]),
                    fminf(red[threadIdx.x][2],red[threadIdx.x][3]));
    minsW[blockIdx.x*3 + threadIdx.x] = m;
  }
}

// ---------------- sort stage 1+2 fused: min-reduce + keys + grid coords + bitonic 1024-runs ----------------
__global__ __launch_bounds__(512) void bsort_keys_kernel(const float* __restrict__ xyz, const float* __restrict__ minsW,
        u64* __restrict__ keys, int* __restrict__ gridO, int N)
{
  __shared__ u64 sk[1024];
  __shared__ float mnS[3];
  int t = threadIdx.x, bid = blockIdx.x;
  // reduce 64 per-block mins per axis (threads 0..191; each 64-thread wave = one axis)
  if (t < 192){
    float v = minsW[(t&63)*3 + (t>>6)];
    #pragma unroll
    for (int s=1;s<64;s<<=1) v = fminf(v, __shfl_xor(v,s));
    if ((t&63)==0) mnS[t>>6] = v;
  }
  __syncthreads();
  float mx0=mnS[0], mx1=mnS[1], mx2=mnS[2];
  int i0 = bid*1024;
  #pragma unroll
  for (int p=0;p<2;p++){
    int i = i0 + t + p*512;
    int gx=(int)((xyz[i]-mx0)/0.02f);     gx = gx<0?0:(gx>65535?65535:gx);
    int gy=(int)((xyz[N+i]-mx1)/0.02f);   gy = gy<0?0:(gy>65535?65535:gy);
    int gz=(int)((xyz[2*N+i]-mx2)/0.02f); gz = gz<0?0:(gz>65535?65535:gz);
    gridO[i*3+0]=gx; gridO[i*3+1]=gy; gridO[i*3+2]=gz;
    u64 mort = (spread3((u32)gx)<<2)|(spread3((u32)gy)<<1)|spread3((u32)gz);
    sk[t + p*512] = (mort<<14) | (u64)i;   // stable tie-break = ascending index
  }
  for (int size=2; size<=1024; size<<=1){
    for (int stride=size>>1; stride>0; stride>>=1){
      __syncthreads();
      int i = 2*t - (t & (stride-1));
      int j = i + stride;
      u64 a = sk[i], b = sk[j];
      bool up = ((i & size) == 0);
      if ((a > b) == up){ sk[i]=b; sk[j]=a; }
    }
  }
  __syncthreads();
  keys[i0 + t] = sk[t];
  keys[i0 + 512 + t] = sk[t+512];
}

// ---------------- sort stage 3: merge-path pairwise merge (4 outs/thread); FINAL emits order+iorder ----------------
template<bool FINAL>
__global__ __launch_bounds__(256) void merge_kernel(const u64* __restrict__ src, u64* __restrict__ dst,
        int* __restrict__ order, int* __restrict__ iorder, int L, int N)
{
  int gt = blockIdx.x*256 + threadIdx.x;
  int d0 = gt*4;
  if (d0 >= N) return;
  int pair = d0 / (2*L);
  int base = pair*2*L;
  int ld = d0 - base;
  const u64* A = src + base;
  const u64* B = A + L;
  int lo = ld > L ? ld - L : 0;
  int hi = ld < L ? ld : L;
  while (lo < hi){
    int mid = (lo+hi)>>1;
    if (A[mid] <= B[ld-1-mid]) lo = mid+1; else hi = mid;
  }
  int i = lo, j = ld - lo;
  u64* out = dst + base + ld;
  int* oout = order + base + ld;
  u64 a = (i < L) ? A[i] : ~0ull;
  u64 b = (j < L) ? B[j] : ~0ull;
  #pragma unroll
  for (int e=0;e<4;e++){
    u64 v;
    if (a <= b){ v = a; i++; a = (i<L)?A[i]:~0ull; }
    else       { v = b; j++; b = (j<L)?B[j]:~0ull; }
    out[e] = v;
    if (FINAL){
      int orig = (int)(v & 16383ull);
      oout[e] = orig;
      iorder[orig] = base + ld + e;
    }
  }
}

// ---------------- all 4 weight transposes -> bf16 (Nout, K), one launch ----------------
__global__ __launch_bounds__(256) void wtrans4_kernel(const float* __restrict__ qkv_w, const float* __restrict__ proj_w,
    const float* __restrict__ w1, const float* __restrict__ w2,
    u16* __restrict__ qkv_wT, u16* __restrict__ proj_wT, u16* __restrict__ w1T, u16* __restrict__ w2T)
{
  __shared__ float tl[32][33];
  int bid = blockIdx.x;
  const float* W; u16* Wt; int K, Nc, lb;
  if (bid < 432)      { W=qkv_w;  Wt=qkv_wT;  K=384;  Nc=1152; lb=bid; }
  else if (bid < 576) { W=proj_w; Wt=proj_wT; K=384;  Nc=384;  lb=bid-432; }
  else if (bid < 1152){ W=w1;     Wt=w1T;     K=384;  Nc=1536; lb=bid-576; }
  else                { W=w2;     Wt=w2T;     K=1536; Nc=384;  lb=bid-1152; }
  int nb = Nc/32;
  int n0 = (lb % nb)*32;
  int k0 = (lb / nb)*32;
  int t=threadIdx.x; int r=t>>5, c=t&31;
  #pragma unroll
  for (int p=0;p<4;p++) tl[p*8+r][c] = W[(size_t)(k0+p*8+r)*Nc + n0+c];
  __syncthreads();
  #pragma unroll
  for (int p=0;p<4;p++) Wt[(size_t)(n0+p*8+r)*K + k0+c] = f2bf(tl[c][p*8+r]);
}

// ---------------- LN fused with (C,N)->(N,C) transpose, 32-token tiles ----------------
template<bool BF16IN>
__global__ __launch_bounds__(256) void ln32_kernel(const void* __restrict__ xin, const float* __restrict__ g,
     const float* __restrict__ b, u16* __restrict__ xn, int N)
{
  extern __shared__ char dsm[];
  float* tile = (float*)dsm; // [32][388]
  int n0 = blockIdx.x*32;
  int t = threadIdx.x;
  int tok32 = t&31, cg2 = t>>5;
  #pragma unroll 8
  for (int p=0;p<48;p++){
    int cc = p*8 + cg2;
    float v;
    if (BF16IN) v = bf2f(((const u16*)xin)[(size_t)cc*N + n0 + tok32]);
    else        v = ((const float*)xin)[(size_t)cc*N + n0 + tok32];
    tile[tok32*388 + cc] = v;
  }
  __syncthreads();
  int tok = t>>3, part = t&7;
  const float* row = tile + tok*388 + part*48;
  float s=0.f;
  #pragma unroll
  for (int j=0;j<48;j++) s += row[j];
  s += __shfl_xor(s,1); s += __shfl_xor(s,2); s += __shfl_xor(s,4);
  float mu = s*(1.0f/384.0f);
  float vr=0.f;
  #pragma unroll
  for (int j=0;j<48;j++){ float d=row[j]-mu; vr += d*d; }
  vr += __shfl_xor(vr,1); vr += __shfl_xor(vr,2); vr += __shfl_xor(vr,4);
  float rs = rsqrtf(vr*(1.0f/384.0f) + 1e-5f);
  u16* dst = xn + (size_t)(n0+tok)*384 + part*48;
  #pragma unroll
  for (int q=0;q<6;q++){
    float v[8];
    #pragma unroll
    for (int j=0;j<8;j++){
      int c = part*48 + q*8 + j;
      v[j] = (row[q*8+j]-mu)*rs*g[c] + b[c];
    }
    ux4 o;
    o[0]=cvtpk(v[0],v[1]); o[1]=cvtpk(v[2],v[3]); o[2]=cvtpk(v[4],v[5]); o[3]=cvtpk(v[6],v[7]);
    *(ux4*)(dst + q*8) = o;
  }
}

__device__ __forceinline__ float gelu_f(float v){
  return 0.5f*v*(1.0f + erff(v*0.7071067811865475f));
}

#define LOG2_100_O8 0.8304820237218405f   // log2(100)/8; invf = exp2(-fi * this)

// ---------------- 256x128 QKV GEMM with fused RoPE + sorted scatter to Qp/Kp/Vp ----------------
__global__ __launch_bounds__(512) void gemm256qkv_kernel(const u16* __restrict__ A, const u16* __restrict__ Bt,
    const float* __restrict__ bias, const int* __restrict__ iorder, const int* __restrict__ gridO,
    u16* __restrict__ Qp, u16* __restrict__ Kp, u16* __restrict__ Vp, int M, int K)
{
  __shared__ u16 Al[256*64];
  __shared__ u16 Bl[128*64];
  int nmt = M>>8;
  int m0 = (blockIdx.x % nmt)<<8;
  int n0 = (blockIdx.x / nmt)<<7;
  int t = threadIdx.x, lane=t&63, wv=t>>6, wr=wv>>1, wc=wv&1;
  int fr = lane&15, fg = lane>>4;
  fx4 acc[4][4];
  #pragma unroll
  for (int i=0;i<4;i++)
  #pragma unroll
  for (int j=0;j<4;j++) acc[i][j]=(fx4){0.f,0.f,0.f,0.f};
  int srowA = wv*32 + (lane>>3);
  int srowB = wv*16 + (lane>>3);
  int swz  = ((lane&7) ^ ((lane>>3)&7)) * 8;       // u16 col
  const u16* ApL = A  + (size_t)(m0+srowA)*K + swz;
  const u16* BpL = Bt + (size_t)(n0+srowB)*K + swz;
  u16* AlW = Al + wv*2048 + lane*8;
  u16* BlW = Bl + wv*1024 + lane*8;
  const u16* a_base = Al + (wr*64+fr)*64;
  const u16* b_base = Bl + (wc*64+fr)*64;
  int swr = fr & 7;
  for (int k0=0;k0<K;k0+=64){
    #pragma unroll
    for (int i=0;i<4;i++) gload16(ApL + k0 + (size_t)i*8*K, AlW + i*512);
    #pragma unroll
    for (int i=0;i<2;i++) gload16(BpL + k0 + (size_t)i*8*K, BlW + i*512);
    __syncthreads();
    #pragma unroll
    for (int ks=0;ks<2;ks++){
      int soff = (((ks*4+fg) ^ swr) << 3);
      s16x8 a[4], b[4];
      #pragma unroll
      for (int mi=0;mi<4;mi++) a[mi] = *(const s16x8*)(a_base + mi*1024 + soff);
      #pragma unroll
      for (int ni=0;ni<4;ni++) b[ni] = *(const s16x8*)(b_base + ni*1024 + soff);
      #pragma unroll
      for (int mi=0;mi<4;mi++)
      #pragma unroll
      for (int ni=0;ni<4;ni++)
        acc[mi][ni] = __builtin_amdgcn_mfma_f32_16x16x32_bf16(a[mi], b[ni], acc[mi][ni], 0,0,0);
    }
    __syncthreads();
  }
  // epilogue: bias + RoPE(q,k) + scatter to sorted rows
  float invf = __builtin_amdgcn_exp2f(-(float)(fr&7) * LOG2_100_O8);
  bool hiLane = (fr & 8) != 0;
  #pragma unroll
  for (int mi=0;mi<4;mi++){
    int tokb = m0 + wr*64 + mi*16 + fg*4;
    int io4[4];
    #pragma unroll
    for (int j=0;j<4;j++) io4[j] = iorder[tokb+j];
    #pragma unroll
    for (int ni=0;ni<4;ni++){
      int c = n0 + wc*64 + ni*16 + fr;
      float bi = bias[c];
      int sec = c/384;                 // uniform across the 16 lanes of this fragment
      int rem = c - sec*384;
      int h = rem/48;
      int a = (rem%48)>>4;
      u16* dst = (sec==0) ? Qp : ((sec==1) ? Kp : Vp);
      #pragma unroll
      for (int j=0;j<4;j++){
        float v = acc[mi][ni][j] + bi;
        float outv;
        if (sec < 2){
          int pos = gridO[(tokb+j)*3 + a];
          pos = pos>4095?4095:pos;
          float ang = (float)pos * invf;
          float cs = __cosf(ang), sn = __sinf(ang);
          float p = __shfl_xor(v, 8);
          outv = hiLane ? (v*cs + p*sn) : (v*cs - p*sn);
        } else {
          outv = v;
        }
        dst[((size_t)h*M + io4[j])*48 + a*16 + fr] = f2bf(outv);
      }
    }
  }
}

// ---------------- 256x128 MFMA GEMM (512 thr, 8 waves) for FFN1 ----------------
// EPI 1: outB bf16 (M,Nout) = gelu(acc+bias)
template<int EPI>
__global__ __launch_bounds__(512) void gemm256_kernel(const u16* __restrict__ A, const u16* __restrict__ Bt,
    const float* __restrict__ bias, u16* __restrict__ outB, int M, int Nout, int K)
{
  __shared__ u16 Al[256*64];
  __shared__ u16 Bl[128*64];
  int nmt = M>>8;
  int m0 = (blockIdx.x % nmt)<<8;
  int n0 = (blockIdx.x / nmt)<<7;
  int t = threadIdx.x, lane=t&63, wv=t>>6, wr=wv>>1, wc=wv&1;
  int fr = lane&15, fg = lane>>4;
  fx4 acc[4][4];
  #pragma unroll
  for (int i=0;i<4;i++)
  #pragma unroll
  for (int j=0;j<4;j++) acc[i][j]=(fx4){0.f,0.f,0.f,0.f};
  int srowA = wv*32 + (lane>>3);
  int srowB = wv*16 + (lane>>3);
  int swz  = ((lane&7) ^ ((lane>>3)&7)) * 8;       // u16 col
  const u16* ApL = A  + (size_t)(m0+srowA)*K + swz;
  const u16* BpL = Bt + (size_t)(n0+srowB)*K + swz;
  u16* AlW = Al + wv*2048 + lane*8;
  u16* BlW = Bl + wv*1024 + lane*8;
  const u16* a_base = Al + (wr*64+fr)*64;
  const u16* b_base = Bl + (wc*64+fr)*64;
  int swr = fr & 7;
  for (int k0=0;k0<K;k0+=64){
    #pragma unroll
    for (int i=0;i<4;i++) gload16(ApL + k0 + (size_t)i*8*K, AlW + i*512);
    #pragma unroll
    for (int i=0;i<2;i++) gload16(BpL + k0 + (size_t)i*8*K, BlW + i*512);
    __syncthreads();                      // drains vmcnt -> tile resident
    #pragma unroll
    for (int ks=0;ks<2;ks++){
      int soff = (((ks*4+fg) ^ swr) << 3);
      s16x8 a[4], b[4];
      #pragma unroll
      for (int mi=0;mi<4;mi++) a[mi] = *(const s16x8*)(a_base + mi*1024 + soff);
      #pragma unroll
      for (int ni=0;ni<4;ni++) b[ni] = *(const s16x8*)(b_base + ni*1024 + soff);
      #pragma unroll
      for (int mi=0;mi<4;mi++)
      #pragma unroll
      for (int ni=0;ni<4;ni++)
        acc[mi][ni] = __builtin_amdgcn_mfma_f32_16x16x32_bf16(a[mi], b[ni], acc[mi][ni], 0,0,0);
    }
    __syncthreads();                      // all reads done before next overwrite
  }
  #pragma unroll
  for (int mi=0;mi<4;mi++)
  #pragma unroll
  for (int ni=0;ni<4;ni++){
    int c = n0 + wc*64 + ni*16 + fr;
    float bi = bias[c];
    int mb = m0 + wr*64 + mi*16 + fg*4;
    #pragma unroll
    for (int j=0;j<4;j++){
      float vv = acc[mi][ni][j] + bi;
      if (EPI==1) vv = gelu_f(vv);
      outB[(size_t)(mb+j)*Nout + c] = f2bf(vv);
    }
  }
}

// ---------------- 128x128 MFMA GEMM, pipelined dbuf BK=64 (stage next before compute) ----------------
// EPI 2: outB bf16 (C,M) = acc+bias+resF[c*M+m]              (proj -> y1 bf16, res = x f32)
// EPI 3: outF f32  (C,M) = acc+bias+bf2f(resB[c*M+m])        (FFN2 -> d_out, res = y1 bf16)
template<int EPI>
__global__ __launch_bounds__(256) void gemm128p_kernel(const u16* __restrict__ A, const u16* __restrict__ Bt,
    const float* __restrict__ bias, u16* __restrict__ outB, float* __restrict__ outF,
    const float* __restrict__ resF, const u16* __restrict__ resB, int M, int Nout, int K)
{
  __shared__ u16 Al[2][128*64];
  __shared__ u16 Bl[2][128*64];
  int nmt = M>>7;
  int m0 = (blockIdx.x % nmt)<<7;
  int n0 = (blockIdx.x / nmt)<<7;
  int t = threadIdx.x, lane=t&63, wv=t>>6, wr=wv>>1, wc=wv&1;
  int fr = lane&15, fg = lane>>4;
  fx4 acc[4][4];
  #pragma unroll
  for (int i=0;i<4;i++)
  #pragma unroll
  for (int j=0;j<4;j++) acc[i][j]=(fx4){0.f,0.f,0.f,0.f};
  int srow = wv*32 + (lane>>3);
  int swz  = ((lane&7) ^ ((lane>>3)&7)) * 8;       // u16 col
  const u16* ApL = A  + (size_t)(m0+srow)*K + swz;
  const u16* BpL = Bt + (size_t)(n0+srow)*K + swz;
  int woff = wv*2048 + lane*8;
  int swr = fr & 7;
  // prologue: stage k=0 into buf0
  #pragma unroll
  for (int i=0;i<4;i++){
    gload16(ApL + (size_t)i*8*K, Al[0] + woff + i*512);
    gload16(BpL + (size_t)i*8*K, Bl[0] + woff + i*512);
  }
  __syncthreads();
  int niter = K>>6;
  for (int it=0; it<niter; ++it){
    int cur = it & 1;
    if (it+1 < niter){
      // T3: issue next-tile loads BEFORE compute -> HBM latency hides under MFMA
      int k1 = (it+1)<<6;
      #pragma unroll
      for (int i=0;i<4;i++){
        gload16(ApL + k1 + (size_t)i*8*K, Al[cur^1] + woff + i*512);
        gload16(BpL + k1 + (size_t)i*8*K, Bl[cur^1] + woff + i*512);
      }
    }
    const u16* a_base = Al[cur] + (wr*64+fr)*64;
    const u16* b_base = Bl[cur] + (wc*64+fr)*64;
    #pragma unroll
    for (int ks=0;ks<2;ks++){
      int soff = (((ks*4+fg) ^ swr) << 3);
      s16x8 a[4], b[4];
      #pragma unroll
      for (int mi=0;mi<4;mi++) a[mi] = *(const s16x8*)(a_base + mi*1024 + soff);
      #pragma unroll
      for (int ni=0;ni<4;ni++) b[ni] = *(const s16x8*)(b_base + ni*1024 + soff);
      #pragma unroll
      for (int mi=0;mi<4;mi++)
      #pragma unroll
      for (int ni=0;ni<4;ni++)
        acc[mi][ni] = __builtin_amdgcn_mfma_f32_16x16x32_bf16(a[mi], b[ni], acc[mi][ni], 0,0,0);
    }
    __syncthreads();   // drains vmcnt (loads had a full MFMA phase of head start) + buffer handoff
  }
  if (EPI==2){
    #pragma unroll
    for (int mi=0;mi<4;mi++)
    #pragma unroll
    for (int ni=0;ni<4;ni++){
      int c = n0 + wc*64 + ni*16 + fr;
      float bi = bias[c];
      size_t idx = (size_t)c*M + m0 + wr*64 + mi*16 + fg*4;
      fx4 r4 = *(const fx4*)(resF + idx);
      ux2 p;
      p[0] = cvtpk(acc[mi][ni][0]+bi+r4[0], acc[mi][ni][1]+bi+r4[1]);
      p[1] = cvtpk(acc[mi][ni][2]+bi+r4[2], acc[mi][ni][3]+bi+r4[3]);
      *(ux2*)(outB + idx) = p;
    }
  } else {
    #pragma unroll
    for (int mi=0;mi<4;mi++)
    #pragma unroll
    for (int ni=0;ni<4;ni++){
      int c = n0 + wc*64 + ni*16 + fr;
      float bi = bias[c];
      size_t idx = (size_t)c*M + m0 + wr*64 + mi*16 + fg*4;
      ux2 rb = *(const ux2*)(resB + idx);
      fx4 o;
      o[0] = acc[mi][ni][0] + bi + bf2f((u16)rb[0]);
      o[1] = acc[mi][ni][1] + bi + bf2f((u16)(rb[0]>>16));
      o[2] = acc[mi][ni][2] + bi + bf2f((u16)rb[1]);
      o[3] = acc[mi][ni][3] + bi + bf2f((u16)(rb[1]>>16));
      *(fx4*)(outF + idx) = o;
    }
  }
}

// ---------------- windowed attention: 8 waves, dbuf K/V staging, MFMA row-sums ----------------
#define ATTN_SCALE 0.14433756729740643f
#define E2SCALE 0.2082354550504211f     // ATTN_SCALE * log2(e)
#define DEFER_RAW 55.0f                 // 8 / ATTN_SCALE (P bounded by e^8, safe in bf16)
#define KSTRIDE 68

__global__ __launch_bounds__(512) void attn7_kernel(const u16* __restrict__ Qp, const u16* __restrict__ Kp,
    const u16* __restrict__ Vp, const int* __restrict__ order, u16* __restrict__ attn, int N, int nw)
{
  __shared__ u16 Kl[2][64*KSTRIDE];    // [key64][d64] stride 68, cols 48-63 zero
  __shared__ u16 Vl[2][48*KSTRIDE];    // [d48][key64^swz] stride 68
  __shared__ u16 Pl[8][32*KSTRIDE];    // per-wave P [q32][key64] stride 68
  int b = blockIdx.x;
  int hw = b & 127;                    // same hw -> same bid%8 -> same XCD (K/V L2 reuse)
  int qc = b >> 7;
  int w = hw % nw, h = hw / nw;
  int t = threadIdx.x, lane = t&63, wv = t>>6;
  int fr = lane & 15, fg = lane >> 4;
  size_t base = ((size_t)h*N + (size_t)w*1024);
  int q0 = qc*256 + wv*32;
  bool kact = t < 384;
  int krow = t/6, kc = t - krow*6;
  const u16* ksrc = Kp + (base + krow)*48 + kc*8;
  int koff = krow*KSTRIDE + kc*8;
  int s2 = t - 128;
  bool vact = t >= 128;
  int vrow = s2/6, vc = s2 - vrow*6;
  const u16* vsrc = Vp + (base + vrow)*48 + vc*8;
  int vkey = vrow ^ (vc<<3);           // swizzled key column (store side)
  if (t < 256){
    ux2 z = {0,0};
    *(ux2*)&Kl[0][(t>>2)*KSTRIDE + 48 + (t&3)*4] = z;
    *(ux2*)&Kl[1][(t>>2)*KSTRIDE + 48 + (t&3)*4] = z;
  }
  s16x8 qf[2][2];
  s16x8 zf = {0,0,0,0,0,0,0,0};
  #pragma unroll
  for (int n=0;n<2;n++){
    const u16* qrow = Qp + (base + q0 + n*16 + fr)*48;
    qf[n][0] = ld_bf8(qrow + fg*8);
    qf[n][1] = (fg < 2) ? ld_bf8(qrow + 32 + fg*8) : zf;
  }
  s16x8 ones;
  #pragma unroll
  for (int j=0;j<8;j++) ones[j] = (short)0x3F80;

  float m0r = -3.4e38f, m1r = -3.4e38f;
  fx4 o00=(fx4){0.f,0.f,0.f,0.f}, o01=o00, o02=o00, o03=o00, o10=o00, o11=o00, o12=o00, o13=o00;
  u16* pl = Pl[wv];
  ux4 kreg = {0,0,0,0}, vreg = {0,0,0,0};
  if (kact) kreg = *(const ux4*)ksrc;
  if (vact) vreg = *(const ux4*)vsrc;
  if (kact){
    ux2 lo; lo[0]=kreg[0]; lo[1]=kreg[1];
    ux2 hi; hi[0]=kreg[2]; hi[1]=kreg[3];
    *(ux2*)(Kl[0]+koff) = lo; *(ux2*)(Kl[0]+koff+4) = hi;
  }
  if (vact){
    u16* vcp = Vl[0] + vkey;
    vcp[(vc*8+0)*KSTRIDE] = (u16)vreg[0];
    vcp[(vc*8+1)*KSTRIDE] = (u16)(vreg[0]>>16);
    vcp[(vc*8+2)*KSTRIDE] = (u16)vreg[1];
    vcp[(vc*8+3)*KSTRIDE] = (u16)(vreg[1]>>16);
    vcp[(vc*8+4)*KSTRIDE] = (u16)vreg[2];
    vcp[(vc*8+5)*KSTRIDE] = (u16)(vreg[2]>>16);
    vcp[(vc*8+6)*KSTRIDE] = (u16)vreg[3];
    vcp[(vc*8+7)*KSTRIDE] = (u16)(vreg[3]>>16);
  }
  __syncthreads();

  for (int c=0;c<16;c++){
    int cur = c & 1;
    const u16* kl = Kl[cur];
    const u16* vl = Vl[cur];
    if (c < 15){
      if (kact) kreg = *(const ux4*)(ksrc + (size_t)(c+1)*3072);
      if (vact) vreg = *(const ux4*)(vsrc + (size_t)(c+1)*3072);
    }
    fx4 s0[4], s1v[4];
    __builtin_amdgcn_s_setprio(1);
    #pragma unroll
    for (int m=0;m<4;m++){
      s0[m]=(fx4){0.f,0.f,0.f,0.f}; s1v[m]=s0[m];
      #pragma unroll
      for (int s=0;s<2;s++){
        s16x8 af = ld_bf8(kl + (m*16+fr)*KSTRIDE + s*32 + fg*8);
        s0[m]  = __builtin_amdgcn_mfma_f32_16x16x32_bf16(af, qf[0][s], s0[m],  0,0,0);
        s1v[m] = __builtin_amdgcn_mfma_f32_16x16x32_bf16(af, qf[1][s], s1v[m], 0,0,0);
      }
    }
    __builtin_amdgcn_s_setprio(0);
    float pm0 = -3.4e38f, pm1 = -3.4e38f;
    #pragma unroll
    for (int m=0;m<4;m++){
      float a0 = fmaxf(fmaxf(s0[m][0],s0[m][1]), fmaxf(s0[m][2],s0[m][3]));
      float a1 = fmaxf(fmaxf(s1v[m][0],s1v[m][1]), fmaxf(s1v[m][2],s1v[m][3]));
      pm0 = fmaxf(pm0, a0); pm1 = fmaxf(pm1, a1);
    }
    pm0 = fmaxf(pm0, __shfl_xor(pm0,16)); pm0 = fmaxf(pm0, __shfl_xor(pm0,32));
    pm1 = fmaxf(pm1, __shfl_xor(pm1,16)); pm1 = fmaxf(pm1, __shfl_xor(pm1,32));
    if (!__all((pm0 <= m0r + DEFER_RAW) & (pm1 <= m1r + DEFER_RAW))){
      float nm0 = fmaxf(m0r, pm0), nm1 = fmaxf(m1r, pm1);
      float f0 = __builtin_amdgcn_exp2f((m0r - nm0)*E2SCALE);
      float f1 = __builtin_amdgcn_exp2f((m1r - nm1)*E2SCALE);
      m0r = nm0; m1r = nm1;
      #pragma unroll
      for (int j=0;j<4;j++){
        float g0 = __shfl(f0, fg*4+j);
        float g1 = __shfl(f1, fg*4+j);
        o00[j]*=g0; o01[j]*=g0; o02[j]*=g0; o03[j]*=g0;
        o10[j]*=g1; o11[j]*=g1; o12[j]*=g1; o13[j]*=g1;
      }
    }
    #pragma unroll
    for (int m=0;m<4;m++){
      float e0[4], e1[4];
      #pragma unroll
      for (int j=0;j<4;j++){
        e0[j] = __builtin_amdgcn_exp2f((s0[m][j]-m0r)*E2SCALE);
        e1[j] = __builtin_amdgcn_exp2f((s1v[m][j]-m1r)*E2SCALE);
      }
      ux2 P0, P1;
      P0[0]=cvtpk(e0[0],e0[1]); P0[1]=cvtpk(e0[2],e0[3]);
      P1[0]=cvtpk(e1[0],e1[1]); P1[1]=cvtpk(e1[2],e1[3]);
      *(ux2*)&pl[(fr)*KSTRIDE + m*16 + fg*4]      = P0;
      *(ux2*)&pl[(16+fr)*KSTRIDE + m*16 + fg*4]   = P1;
    }
    __builtin_amdgcn_s_setprio(1);
    #pragma unroll
    for (int s=0;s<2;s++){
      int kb = s*32 + fg*8;
      s16x8 pa0 = ld_bf8(pl + fr*KSTRIDE + kb);
      s16x8 pa1 = ld_bf8(pl + (16+fr)*KSTRIDE + kb);
      s16x8 vb0 = ld_bf8(vl + (fr)*KSTRIDE    + (kb ^ ((fr)&56)));
      s16x8 vb1 = ld_bf8(vl + (16+fr)*KSTRIDE + (kb ^ ((16+fr)&56)));
      s16x8 vb2 = ld_bf8(vl + (32+fr)*KSTRIDE + (kb ^ ((32+fr)&56)));
      o00 = __builtin_amdgcn_mfma_f32_16x16x32_bf16(pa0, vb0, o00, 0,0,0);
      o01 = __builtin_amdgcn_mfma_f32_16x16x32_bf16(pa0, vb1, o01, 0,0,0);
      o02 = __builtin_amdgcn_mfma_f32_16x16x32_bf16(pa0, vb2, o02, 0,0,0);
      o03 = __builtin_amdgcn_mfma_f32_16x16x32_bf16(pa0, ones, o03, 0,0,0);
      o10 = __builtin_amdgcn_mfma_f32_16x16x32_bf16(pa1, vb0, o10, 0,0,0);
      o11 = __builtin_amdgcn_mfma_f32_16x16x32_bf16(pa1, vb1, o11, 0,0,0);
      o12 = __builtin_amdgcn_mfma_f32_16x16x32_bf16(pa1, vb2, o12, 0,0,0);
      o13 = __builtin_amdgcn_mfma_f32_16x16x32_bf16(pa1, ones, o13, 0,0,0);
    }
    __builtin_amdgcn_s_setprio(0);
    if (c < 15){
      u16* kln = Kl[cur^1];
      u16* vln = Vl[cur^1];
      if (kact){
        ux2 lo; lo[0]=kreg[0]; lo[1]=kreg[1];
        ux2 hi; hi[0]=kreg[2]; hi[1]=kreg[3];
        *(ux2*)(kln+koff) = lo; *(ux2*)(kln+koff+4) = hi;
      }
      if (vact){
        u16* vcp = vln + vkey;
        vcp[(vc*8+0)*KSTRIDE] = (u16)vreg[0];
        vcp[(vc*8+1)*KSTRIDE] = (u16)(vreg[0]>>16);
        vcp[(vc*8+2)*KSTRIDE] = (u16)vreg[1];
        vcp[(vc*8+3)*KSTRIDE] = (u16)(vreg[1]>>16);
        vcp[(vc*8+4)*KSTRIDE] = (u16)vreg[2];
        vcp[(vc*8+5)*KSTRIDE] = (u16)(vreg[2]>>16);
        vcp[(vc*8+6)*KSTRIDE] = (u16)vreg[3];
        vcp[(vc*8+7)*KSTRIDE] = (u16)(vreg[3]>>16);
      }
      __syncthreads();
    }
  }
  const int* ord = order + w*1024 + q0;
  #pragma unroll
  for (int j=0;j<4;j++){
    float inv0 = 1.0f / o03[j];
    float inv1 = 1.0f / o13[j];
    int orig0 = ord[fg*4+j];
    u16* dst0 = attn + (size_t)orig0*384 + h*48;
    dst0[fr]      = f2bf(o00[j]*inv0);
    dst0[16+fr]   = f2bf(o01[j]*inv0);
    dst0[32+fr]   = f2bf(o02[j]*inv0);
    int orig1 = ord[16 + fg*4+j];
    u16* dst1 = attn + (size_t)orig1*384 + h*48;
    dst1[fr]      = f2bf(o10[j]*inv1);
    dst1[16+fr]   = f2bf(o11[j]*inv1);
    dst1[32+fr]   = f2bf(o12[j]*inv1);
  }
}

extern "C" void kernel_launch(void* const* d_in, const int* in_sizes, int n_in,
                              void* d_out, int out_size, void* d_ws, size_t ws_size,
                              hipStream_t stream)
{
  (void)n_in; (void)out_size; (void)ws_size;
  const float* x     = (const float*)d_in[0];
  const float* xyz   = (const float*)d_in[1];
  const float* ln1_g = (const float*)d_in[2];
  const float* ln1_b = (const float*)d_in[3];
  const float* qkv_w = (const float*)d_in[4];
  const float* qkv_b = (const float*)d_in[5];
  const float* proj_w= (const float*)d_in[6];
  const float* proj_b= (const float*)d_in[7];
  const float* ln2_g = (const float*)d_in[8];
  const float* ln2_b = (const float*)d_in[9];
  const float* ffn_w1= (const float*)d_in[10];
  const float* ffn_b1= (const float*)d_in[11];
  const float* ffn_w2= (const float*)d_in[12];
  const float* ffn_b2= (const float*)d_in[13];
  int N = in_sizes[0]/384;
  int nw = N/1024;
  char* wsp = (char*)d_ws;
  size_t off = 0;
  auto alloc = [&](size_t bytes)->char*{ char* p = wsp + off; off = (off + bytes + 255) & ~(size_t)255; return p; };
  int*  order   = (int*)alloc((size_t)N*4);
  int*  iorder  = (int*)alloc((size_t)N*4);
  int*  gridO   = (int*)alloc((size_t)N*12);
  float* minsW  = (float*)alloc((size_t)(N/256)*12);
  u64*  keysA   = (u64*)alloc((size_t)N*8);
  u64*  keysB   = (u64*)alloc((size_t)N*8);
  u16*  qkv_wT  = (u16*)alloc((size_t)1152*384*2);
  u16*  proj_wT = (u16*)alloc((size_t)384*384*2);
  u16*  w1T     = (u16*)alloc((size_t)1536*384*2);
  u16*  w2T     = (u16*)alloc((size_t)384*1536*2);
  // layout so that [xn | Qp | Kp | Vp] is one contiguous region = mid for the FFN
  u16*  xn      = (u16*)alloc((size_t)N*384*2);
  u16*  Qp      = (u16*)alloc((size_t)N*48*8*2);
  u16*  Kp      = (u16*)alloc((size_t)N*48*8*2);
  u16*  Vp      = (u16*)alloc((size_t)N*48*8*2);
  u16*  xn2     = (u16*)alloc((size_t)N*384*2);
  u16*  y1b     = (u16*)alloc((size_t)N*384*2);    // y1 bf16, (C, M) layout
  u16*  attn    = xn;     // xn dead after QKV gemm
  u16*  mid     = xn;     // [xn|Qp|Kp|Vp] = N*1536*2 bytes, all dead when FFN1 runs
  float* outF = (float*)d_out;

  // ---- parallel Z-order sort (atomic-free min; 1024-runs on 16 blocks; 4 merges; final emits order+iorder) ----
  min3_kernel<<<N/256, 256, 0, stream>>>(xyz, minsW, N);
  bsort_keys_kernel<<<N/1024, 512, 0, stream>>>(xyz, minsW, keysA, gridO, N);
  merge_kernel<false><<<N/1024, 256, 0, stream>>>(keysA, keysB, order, iorder, 1024, N);
  merge_kernel<false><<<N/1024, 256, 0, stream>>>(keysB, keysA, order, iorder, 2048, N);
  merge_kernel<false><<<N/1024, 256, 0, stream>>>(keysA, keysB, order, iorder, 4096, N);
  merge_kernel<true><<<N/1024, 256, 0, stream>>>(keysB, keysA, order, iorder, 8192, N);

  wtrans4_kernel<<<1728, 256, 0, stream>>>(qkv_w, proj_w, ffn_w1, ffn_w2, qkv_wT, proj_wT, w1T, w2T);
  ln32_kernel<false><<<N/32, 256, 32*388*4, stream>>>(x, ln1_g, ln1_b, xn, N);
  // QKV GEMM with fused RoPE + sorted scatter
  gemm256qkv_kernel<<<(N/256)*(1152/128), 512, 0, stream>>>(xn, qkv_wT, qkv_b, iorder, gridO, Qp, Kp, Vp, N, 384);
  attn7_kernel<<<8*nw*4, 512, 0, stream>>>(Qp, Kp, Vp, order, attn, N, nw);
  // proj: y1 bf16 (C,M) = x + (attn @ proj_w + b)^T   (pipelined dbuf GEMM)
  gemm128p_kernel<2><<<(N/128)*(384/128), 256, 0, stream>>>(attn, proj_wT, proj_b, y1b, nullptr, x, nullptr, N, 384, 384);
  // LN2 reads y1 bf16 (column layout)
  ln32_kernel<true><<<N/32, 256, 32*388*4, stream>>>(y1b, ln2_g, ln2_b, xn2, N);
  gemm256_kernel<1><<<(N/256)*(1536/128), 512, 0, stream>>>(xn2, w1T, ffn_b1, mid, N, 1536, 384);
  // FFN2: d_out f32 (C,M) = y1 + (mid @ w2 + b2)^T   (pipelined dbuf GEMM)
  gemm128p_kernel<3><<<(N/128)*(384/128), 256, 0, stream>>>(mid, w2T, ffn_b2, nullptr, outF, nullptr, y1b, N, 384, 1536);
}

// Round 20
// 245.175 us; speedup vs baseline: 1.0075x; 1.0075x over previous
//
#include <hip/hip_runtime.h>
#include <hip/hip_bf16.h>

typedef unsigned short u16;
typedef unsigned int u32;
typedef unsigned long long u64;
typedef __attribute__((ext_vector_type(8))) short s16x8;
typedef __attribute__((ext_vector_type(4))) short s16x4;
typedef __attribute__((ext_vector_type(8))) unsigned short u16x8;
typedef __attribute__((ext_vector_type(4))) unsigned short u16x4;
typedef __attribute__((ext_vector_type(4))) float fx4;
typedef __attribute__((ext_vector_type(4))) unsigned int ux4;
typedef __attribute__((ext_vector_type(2))) unsigned int ux2;

__device__ __forceinline__ float bf2f(u16 u){ u32 x=((u32)u)<<16; return __builtin_bit_cast(float,x); }
__device__ __forceinline__ u16 f2bf(float f){ u32 x=__builtin_bit_cast(u32,f); return (u16)((x + 0x7FFFu + ((x>>16)&1u))>>16); }
// packed f32x2 -> bf16x2 (RNE), single HW instr
__device__ __forceinline__ u32 cvtpk(float lo, float hi){
  u32 r; asm("v_cvt_pk_bf16_f32 %0, %1, %2" : "=v"(r) : "v"(lo), "v"(hi)); return r;
}

__device__ __forceinline__ s16x8 ld_bf8(const u16* p){
  s16x4 lo = *(const s16x4*)p;
  s16x4 hi = *(const s16x4*)(p+4);
  s16x8 r;
  r[0]=lo[0]; r[1]=lo[1]; r[2]=lo[2]; r[3]=lo[3];
  r[4]=hi[0]; r[5]=hi[1]; r[6]=hi[2]; r[7]=hi[3];
  return r;
}

// async global->LDS, 16B per lane; LDS dest must be wave-uniform base + lane*16
__device__ __forceinline__ void gload16(const void* g, void* l){
  __builtin_amdgcn_global_load_lds((__attribute__((address_space(1))) void*)g,
                                   (__attribute__((address_space(3))) void*)l, 16, 0, 0);
}

__device__ __forceinline__ u64 spread3(u32 v){
  u64 x = v & 0xFFFFull;
  x = (x | (x<<32)) & 0x001f00000000ffffull;
  x = (x | (x<<16)) & 0x001f0000ff0000ffull;
  x = (x | (x<<8))  & 0x100f00f00f00f00full;
  x = (x | (x<<4))  & 0x10c30c30c30c30c3ull;
  x = (x | (x<<2))  & 0x1249249249249249ull;
  return x;
}

// ---------------- sort stage 0: per-block per-axis min (no atomics, no memset) ----------------
__global__ __launch_bounds__(256) void min3_kernel(const float* __restrict__ xyz, float* __restrict__ minsW, int N)
{
  __shared__ float red[3][4];
  int i = blockIdx.x*256 + threadIdx.x;
  int lane = threadIdx.x&63, wv = threadIdx.x>>6;
  float v0 = xyz[i], v1 = xyz[N+i], v2 = xyz[2*N+i];
  #pragma unroll
  for (int s=1;s<64;s<<=1){
    v0 = fminf(v0, __shfl_xor(v0,s));
    v1 = fminf(v1, __shfl_xor(v1,s));
    v2 = fminf(v2, __shfl_xor(v2,s));
  }
  if (lane==0){ red[0][wv]=v0; red[1][wv]=v1; red[2][wv]=v2; }
  __syncthreads();
  if (threadIdx.x < 3){
    float m = fminf(fminf(red[threadIdx.x][0],red[threadIdx.x][1]),
                    fminf(red[threadIdx.x][2],red[threadIdx.x][3]));
    minsW[blockIdx.x*3 + threadIdx.x] = m;
  }
}

// ---------------- sort stage 1+2 fused: min-reduce + keys + grid coords + bitonic 2048-runs ----------------
__global__ __launch_bounds__(1024) void bsort_keys_kernel(const float* __restrict__ xyz, const float* __restrict__ minsW,
        u64* __restrict__ keys, int* __restrict__ gridO, int N)
{
  __shared__ u64 sk[2048];
  __shared__ float mnS[3];
  int t = threadIdx.x, bid = blockIdx.x;
  // reduce 64 per-block mins per axis (threads 0..191; each 64-thread wave = one axis)
  if (t < 192){
    float v = minsW[(t&63)*3 + (t>>6)];
    #pragma unroll
    for (int s=1;s<64;s<<=1) v = fminf(v, __shfl_xor(v,s));
    if ((t&63)==0) mnS[t>>6] = v;
  }
  __syncthreads();
  float mx0=mnS[0], mx1=mnS[1], mx2=mnS[2];
  int i0 = bid*2048;
  #pragma unroll
  for (int p=0;p<2;p++){
    int i = i0 + t + p*1024;
    int gx=(int)((xyz[i]-mx0)/0.02f);     gx = gx<0?0:(gx>65535?65535:gx);
    int gy=(int)((xyz[N+i]-mx1)/0.02f);   gy = gy<0?0:(gy>65535?65535:gy);
    int gz=(int)((xyz[2*N+i]-mx2)/0.02f); gz = gz<0?0:(gz>65535?65535:gz);
    gridO[i*3+0]=gx; gridO[i*3+1]=gy; gridO[i*3+2]=gz;
    u64 mort = (spread3((u32)gx)<<2)|(spread3((u32)gy)<<1)|spread3((u32)gz);
    sk[t + p*1024] = (mort<<14) | (u64)i;   // stable tie-break = ascending index
  }
  for (int size=2; size<=2048; size<<=1){
    for (int stride=size>>1; stride>0; stride>>=1){
      __syncthreads();
      int i = 2*t - (t & (stride-1));
      int j = i + stride;
      u64 a = sk[i], b = sk[j];
      bool up = ((i & size) == 0);
      if ((a > b) == up){ sk[i]=b; sk[j]=a; }
    }
  }
  __syncthreads();
  keys[i0 + t] = sk[t];
  keys[i0 + 1024 + t] = sk[t+1024];
}

// ---------------- sort stage 3: merge-path pairwise merge (4 outs/thread); FINAL emits order+iorder ----------------
template<bool FINAL>
__global__ __launch_bounds__(256) void merge_kernel(const u64* __restrict__ src, u64* __restrict__ dst,
        int* __restrict__ order, int* __restrict__ iorder, int L, int N)
{
  int gt = blockIdx.x*256 + threadIdx.x;
  int d0 = gt*4;
  if (d0 >= N) return;
  int pair = d0 / (2*L);
  int base = pair*2*L;
  int ld = d0 - base;
  const u64* A = src + base;
  const u64* B = A + L;
  int lo = ld > L ? ld - L : 0;
  int hi = ld < L ? ld : L;
  while (lo < hi){
    int mid = (lo+hi)>>1;
    if (A[mid] <= B[ld-1-mid]) lo = mid+1; else hi = mid;
  }
  int i = lo, j = ld - lo;
  u64* out = dst + base + ld;
  int* oout = order + base + ld;
  u64 a = (i < L) ? A[i] : ~0ull;
  u64 b = (j < L) ? B[j] : ~0ull;
  #pragma unroll
  for (int e=0;e<4;e++){
    u64 v;
    if (a <= b){ v = a; i++; a = (i<L)?A[i]:~0ull; }
    else       { v = b; j++; b = (j<L)?B[j]:~0ull; }
    out[e] = v;
    if (FINAL){
      int orig = (int)(v & 16383ull);
      oout[e] = orig;
      iorder[orig] = base + ld + e;
    }
  }
}

// ---------------- all 4 weight transposes -> bf16 (Nout, K), one launch ----------------
__global__ __launch_bounds__(256) void wtrans4_kernel(const float* __restrict__ qkv_w, const float* __restrict__ proj_w,
    const float* __restrict__ w1, const float* __restrict__ w2,
    u16* __restrict__ qkv_wT, u16* __restrict__ proj_wT, u16* __restrict__ w1T, u16* __restrict__ w2T)
{
  __shared__ float tl[32][33];
  int bid = blockIdx.x;
  const float* W; u16* Wt; int K, Nc, lb;
  if (bid < 432)      { W=qkv_w;  Wt=qkv_wT;  K=384;  Nc=1152; lb=bid; }
  else if (bid < 576) { W=proj_w; Wt=proj_wT; K=384;  Nc=384;  lb=bid-432; }
  else if (bid < 1152){ W=w1;     Wt=w1T;     K=384;  Nc=1536; lb=bid-576; }
  else                { W=w2;     Wt=w2T;     K=1536; Nc=384;  lb=bid-1152; }
  int nb = Nc/32;
  int n0 = (lb % nb)*32;
  int k0 = (lb / nb)*32;
  int t=threadIdx.x; int r=t>>5, c=t&31;
  #pragma unroll
  for (int p=0;p<4;p++) tl[p*8+r][c] = W[(size_t)(k0+p*8+r)*Nc + n0+c];
  __syncthreads();
  #pragma unroll
  for (int p=0;p<4;p++) Wt[(size_t)(n0+p*8+r)*K + k0+c] = f2bf(tl[c][p*8+r]);
}

// ---------------- LN fused with (C,N)->(N,C) transpose, 32-token tiles ----------------
template<bool BF16IN>
__global__ __launch_bounds__(256) void ln32_kernel(const void* __restrict__ xin, const float* __restrict__ g,
     const float* __restrict__ b, u16* __restrict__ xn, int N)
{
  extern __shared__ char dsm[];
  float* tile = (float*)dsm; // [32][388]
  int n0 = blockIdx.x*32;
  int t = threadIdx.x;
  int tok32 = t&31, cg2 = t>>5;
  #pragma unroll 8
  for (int p=0;p<48;p++){
    int cc = p*8 + cg2;
    float v;
    if (BF16IN) v = bf2f(((const u16*)xin)[(size_t)cc*N + n0 + tok32]);
    else        v = ((const float*)xin)[(size_t)cc*N + n0 + tok32];
    tile[tok32*388 + cc] = v;
  }
  __syncthreads();
  int tok = t>>3, part = t&7;
  const float* row = tile + tok*388 + part*48;
  float s=0.f;
  #pragma unroll
  for (int j=0;j<48;j++) s += row[j];
  s += __shfl_xor(s,1); s += __shfl_xor(s,2); s += __shfl_xor(s,4);
  float mu = s*(1.0f/384.0f);
  float vr=0.f;
  #pragma unroll
  for (int j=0;j<48;j++){ float d=row[j]-mu; vr += d*d; }
  vr += __shfl_xor(vr,1); vr += __shfl_xor(vr,2); vr += __shfl_xor(vr,4);
  float rs = rsqrtf(vr*(1.0f/384.0f) + 1e-5f);
  u16* dst = xn + (size_t)(n0+tok)*384 + part*48;
  #pragma unroll
  for (int q=0;q<6;q++){
    float v[8];
    #pragma unroll
    for (int j=0;j<8;j++){
      int c = part*48 + q*8 + j;
      v[j] = (row[q*8+j]-mu)*rs*g[c] + b[c];
    }
    ux4 o;
    o[0]=cvtpk(v[0],v[1]); o[1]=cvtpk(v[2],v[3]); o[2]=cvtpk(v[4],v[5]); o[3]=cvtpk(v[6],v[7]);
    *(ux4*)(dst + q*8) = o;
  }
}

__device__ __forceinline__ float gelu_f(float v){
  return 0.5f*v*(1.0f + erff(v*0.7071067811865475f));
}

#define LOG2_100_O8 0.8304820237218405f   // log2(100)/8; invf = exp2(-fi * this)

// ---------------- 256x128 QKV GEMM with fused RoPE + sorted scatter to Qp/Kp/Vp ----------------
__global__ __launch_bounds__(512) void gemm256qkv_kernel(const u16* __restrict__ A, const u16* __restrict__ Bt,
    const float* __restrict__ bias, const int* __restrict__ iorder, const int* __restrict__ gridO,
    u16* __restrict__ Qp, u16* __restrict__ Kp, u16* __restrict__ Vp, int M, int K)
{
  __shared__ u16 Al[256*64];
  __shared__ u16 Bl[128*64];
  int nmt = M>>8;
  int m0 = (blockIdx.x % nmt)<<8;
  int n0 = (blockIdx.x / nmt)<<7;
  int t = threadIdx.x, lane=t&63, wv=t>>6, wr=wv>>1, wc=wv&1;
  int fr = lane&15, fg = lane>>4;
  fx4 acc[4][4];
  #pragma unroll
  for (int i=0;i<4;i++)
  #pragma unroll
  for (int j=0;j<4;j++) acc[i][j]=(fx4){0.f,0.f,0.f,0.f};
  int srowA = wv*32 + (lane>>3);
  int srowB = wv*16 + (lane>>3);
  int swz  = ((lane&7) ^ ((lane>>3)&7)) * 8;       // u16 col
  const u16* ApL = A  + (size_t)(m0+srowA)*K + swz;
  const u16* BpL = Bt + (size_t)(n0+srowB)*K + swz;
  u16* AlW = Al + wv*2048 + lane*8;
  u16* BlW = Bl + wv*1024 + lane*8;
  const u16* a_base = Al + (wr*64+fr)*64;
  const u16* b_base = Bl + (wc*64+fr)*64;
  int swr = fr & 7;
  for (int k0=0;k0<K;k0+=64){
    #pragma unroll
    for (int i=0;i<4;i++) gload16(ApL + k0 + (size_t)i*8*K, AlW + i*512);
    #pragma unroll
    for (int i=0;i<2;i++) gload16(BpL + k0 + (size_t)i*8*K, BlW + i*512);
    __syncthreads();
    #pragma unroll
    for (int ks=0;ks<2;ks++){
      int soff = (((ks*4+fg) ^ swr) << 3);
      s16x8 a[4], b[4];
      #pragma unroll
      for (int mi=0;mi<4;mi++) a[mi] = *(const s16x8*)(a_base + mi*1024 + soff);
      #pragma unroll
      for (int ni=0;ni<4;ni++) b[ni] = *(const s16x8*)(b_base + ni*1024 + soff);
      #pragma unroll
      for (int mi=0;mi<4;mi++)
      #pragma unroll
      for (int ni=0;ni<4;ni++)
        acc[mi][ni] = __builtin_amdgcn_mfma_f32_16x16x32_bf16(a[mi], b[ni], acc[mi][ni], 0,0,0);
    }
    __syncthreads();
  }
  // epilogue: bias + RoPE(q,k) + scatter to sorted rows
  float invf = __builtin_amdgcn_exp2f(-(float)(fr&7) * LOG2_100_O8);
  bool hiLane = (fr & 8) != 0;
  #pragma unroll
  for (int mi=0;mi<4;mi++){
    int tokb = m0 + wr*64 + mi*16 + fg*4;
    int io4[4];
    #pragma unroll
    for (int j=0;j<4;j++) io4[j] = iorder[tokb+j];
    #pragma unroll
    for (int ni=0;ni<4;ni++){
      int c = n0 + wc*64 + ni*16 + fr;
      float bi = bias[c];
      int sec = c/384;                 // uniform across the 16 lanes of this fragment
      int rem = c - sec*384;
      int h = rem/48;
      int a = (rem%48)>>4;
      u16* dst = (sec==0) ? Qp : ((sec==1) ? Kp : Vp);
      #pragma unroll
      for (int j=0;j<4;j++){
        float v = acc[mi][ni][j] + bi;
        float outv;
        if (sec < 2){
          int pos = gridO[(tokb+j)*3 + a];
          pos = pos>4095?4095:pos;
          float ang = (float)pos * invf;
          float cs = __cosf(ang), sn = __sinf(ang);
          float p = __shfl_xor(v, 8);
          outv = hiLane ? (v*cs + p*sn) : (v*cs - p*sn);
        } else {
          outv = v;
        }
        dst[((size_t)h*M + io4[j])*48 + a*16 + fr] = f2bf(outv);
      }
    }
  }
}

// ---------------- 256x128 MFMA GEMM (512 thr, 8 waves) for FFN1 ----------------
// EPI 1: outB bf16 (M,Nout) = gelu(acc+bias)
template<int EPI>
__global__ __launch_bounds__(512) void gemm256_kernel(const u16* __restrict__ A, const u16* __restrict__ Bt,
    const float* __restrict__ bias, u16* __restrict__ outB, int M, int Nout, int K)
{
  __shared__ u16 Al[256*64];
  __shared__ u16 Bl[128*64];
  int nmt = M>>8;
  int m0 = (blockIdx.x % nmt)<<8;
  int n0 = (blockIdx.x / nmt)<<7;
  int t = threadIdx.x, lane=t&63, wv=t>>6, wr=wv>>1, wc=wv&1;
  int fr = lane&15, fg = lane>>4;
  fx4 acc[4][4];
  #pragma unroll
  for (int i=0;i<4;i++)
  #pragma unroll
  for (int j=0;j<4;j++) acc[i][j]=(fx4){0.f,0.f,0.f,0.f};
  int srowA = wv*32 + (lane>>3);
  int srowB = wv*16 + (lane>>3);
  int swz  = ((lane&7) ^ ((lane>>3)&7)) * 8;       // u16 col
  const u16* ApL = A  + (size_t)(m0+srowA)*K + swz;
  const u16* BpL = Bt + (size_t)(n0+srowB)*K + swz;
  u16* AlW = Al + wv*2048 + lane*8;
  u16* BlW = Bl + wv*1024 + lane*8;
  const u16* a_base = Al + (wr*64+fr)*64;
  const u16* b_base = Bl + (wc*64+fr)*64;
  int swr = fr & 7;
  for (int k0=0;k0<K;k0+=64){
    #pragma unroll
    for (int i=0;i<4;i++) gload16(ApL + k0 + (size_t)i*8*K, AlW + i*512);
    #pragma unroll
    for (int i=0;i<2;i++) gload16(BpL + k0 + (size_t)i*8*K, BlW + i*512);
    __syncthreads();                      // drains vmcnt -> tile resident
    #pragma unroll
    for (int ks=0;ks<2;ks++){
      int soff = (((ks*4+fg) ^ swr) << 3);
      s16x8 a[4], b[4];
      #pragma unroll
      for (int mi=0;mi<4;mi++) a[mi] = *(const s16x8*)(a_base + mi*1024 + soff);
      #pragma unroll
      for (int ni=0;ni<4;ni++) b[ni] = *(const s16x8*)(b_base + ni*1024 + soff);
      #pragma unroll
      for (int mi=0;mi<4;mi++)
      #pragma unroll
      for (int ni=0;ni<4;ni++)
        acc[mi][ni] = __builtin_amdgcn_mfma_f32_16x16x32_bf16(a[mi], b[ni], acc[mi][ni], 0,0,0);
    }
    __syncthreads();                      // all reads done before next overwrite
  }
  #pragma unroll
  for (int mi=0;mi<4;mi++)
  #pragma unroll
  for (int ni=0;ni<4;ni++){
    int c = n0 + wc*64 + ni*16 + fr;
    float bi = bias[c];
    int mb = m0 + wr*64 + mi*16 + fg*4;
    #pragma unroll
    for (int j=0;j<4;j++){
      float vv = acc[mi][ni][j] + bi;
      if (EPI==1) vv = gelu_f(vv);
      outB[(size_t)(mb+j)*Nout + c] = f2bf(vv);
    }
  }
}

// ---------------- 128x128 MFMA GEMM, BK=128 (two 64-subtiles per barrier pair) ----------------
// EPI 2: outB bf16 (C,M) = acc+bias+resF[c*M+m]              (proj -> y1 bf16, res = x f32)
// EPI 3: outF f32  (C,M) = acc+bias+bf2f(resB[c*M+m])        (FFN2 -> d_out, res = y1 bf16)
template<int EPI>
__global__ __launch_bounds__(256) void gemm128x2_kernel(const u16* __restrict__ A, const u16* __restrict__ Bt,
    const float* __restrict__ bias, u16* __restrict__ outB, float* __restrict__ outF,
    const float* __restrict__ resF, const u16* __restrict__ resB, int M, int Nout, int K)
{
  __shared__ u16 Al[2][128*64];
  __shared__ u16 Bl[2][128*64];
  int nmt = M>>7;
  int m0 = (blockIdx.x % nmt)<<7;
  int n0 = (blockIdx.x / nmt)<<7;
  int t = threadIdx.x, lane=t&63, wv=t>>6, wr=wv>>1, wc=wv&1;
  int fr = lane&15, fg = lane>>4;
  fx4 acc[4][4];
  #pragma unroll
  for (int i=0;i<4;i++)
  #pragma unroll
  for (int j=0;j<4;j++) acc[i][j]=(fx4){0.f,0.f,0.f,0.f};
  int srow = wv*32 + (lane>>3);
  int swz  = ((lane&7) ^ ((lane>>3)&7)) * 8;       // u16 col
  const u16* ApL = A  + (size_t)(m0+srow)*K + swz;
  const u16* BpL = Bt + (size_t)(n0+srow)*K + swz;
  int woff = wv*2048 + lane*8;
  int swr = fr & 7;
  for (int k0=0;k0<K;k0+=128){
    #pragma unroll
    for (int i=0;i<4;i++){
      gload16(ApL + k0 +      (size_t)i*8*K, Al[0] + woff + i*512);
      gload16(BpL + k0 +      (size_t)i*8*K, Bl[0] + woff + i*512);
      gload16(ApL + k0 + 64 + (size_t)i*8*K, Al[1] + woff + i*512);
      gload16(BpL + k0 + 64 + (size_t)i*8*K, Bl[1] + woff + i*512);
    }
    __syncthreads();                      // drains vmcnt -> both subtiles resident
    #pragma unroll
    for (int sub=0;sub<2;sub++){
      const u16* a_base = Al[sub] + (wr*64+fr)*64;
      const u16* b_base = Bl[sub] + (wc*64+fr)*64;
      #pragma unroll
      for (int ks=0;ks<2;ks++){
        int soff = (((ks*4+fg) ^ swr) << 3);
        s16x8 a[4], b[4];
        #pragma unroll
        for (int mi=0;mi<4;mi++) a[mi] = *(const s16x8*)(a_base + mi*1024 + soff);
        #pragma unroll
        for (int ni=0;ni<4;ni++) b[ni] = *(const s16x8*)(b_base + ni*1024 + soff);
        #pragma unroll
        for (int mi=0;mi<4;mi++)
        #pragma unroll
        for (int ni=0;ni<4;ni++)
          acc[mi][ni] = __builtin_amdgcn_mfma_f32_16x16x32_bf16(a[mi], b[ni], acc[mi][ni], 0,0,0);
      }
    }
    __syncthreads();                      // all reads done before next overwrite
  }
  if (EPI==2){
    #pragma unroll
    for (int mi=0;mi<4;mi++)
    #pragma unroll
    for (int ni=0;ni<4;ni++){
      int c = n0 + wc*64 + ni*16 + fr;
      float bi = bias[c];
      size_t idx = (size_t)c*M + m0 + wr*64 + mi*16 + fg*4;
      fx4 r4 = *(const fx4*)(resF + idx);
      ux2 p;
      p[0] = cvtpk(acc[mi][ni][0]+bi+r4[0], acc[mi][ni][1]+bi+r4[1]);
      p[1] = cvtpk(acc[mi][ni][2]+bi+r4[2], acc[mi][ni][3]+bi+r4[3]);
      *(ux2*)(outB + idx) = p;
    }
  } else {
    #pragma unroll
    for (int mi=0;mi<4;mi++)
    #pragma unroll
    for (int ni=0;ni<4;ni++){
      int c = n0 + wc*64 + ni*16 + fr;
      float bi = bias[c];
      size_t idx = (size_t)c*M + m0 + wr*64 + mi*16 + fg*4;
      ux2 rb = *(const ux2*)(resB + idx);
      fx4 o;
      o[0] = acc[mi][ni][0] + bi + bf2f((u16)rb[0]);
      o[1] = acc[mi][ni][1] + bi + bf2f((u16)(rb[0]>>16));
      o[2] = acc[mi][ni][2] + bi + bf2f((u16)rb[1]);
      o[3] = acc[mi][ni][3] + bi + bf2f((u16)(rb[1]>>16));
      *(fx4*)(outF + idx) = o;
    }
  }
}

// ---------------- windowed attention: 8 waves, dbuf K/V staging, MFMA row-sums ----------------
#define ATTN_SCALE 0.14433756729740643f
#define E2SCALE 0.2082354550504211f     // ATTN_SCALE * log2(e)
#define DEFER_RAW 55.0f                 // 8 / ATTN_SCALE (P bounded by e^8, safe in bf16)
#define KSTRIDE 68

__global__ __launch_bounds__(512) void attn7_kernel(const u16* __restrict__ Qp, const u16* __restrict__ Kp,
    const u16* __restrict__ Vp, const int* __restrict__ order, u16* __restrict__ attn, int N, int nw)
{
  __shared__ u16 Kl[2][64*KSTRIDE];    // [key64][d64] stride 68, cols 48-63 zero
  __shared__ u16 Vl[2][48*KSTRIDE];    // [d48][key64^swz] stride 68
  __shared__ u16 Pl[8][32*KSTRIDE];    // per-wave P [q32][key64] stride 68
  int b = blockIdx.x;
  int hw = b & 127;                    // same hw -> same bid%8 -> same XCD (K/V L2 reuse)
  int qc = b >> 7;
  int w = hw % nw, h = hw / nw;
  int t = threadIdx.x, lane = t&63, wv = t>>6;
  int fr = lane & 15, fg = lane >> 4;
  size_t base = ((size_t)h*N + (size_t)w*1024);
  int q0 = qc*256 + wv*32;
  bool kact = t < 384;
  int krow = t/6, kc = t - krow*6;
  const u16* ksrc = Kp + (base + krow)*48 + kc*8;
  int koff = krow*KSTRIDE + kc*8;
  int s2 = t - 128;
  bool vact = t >= 128;
  int vrow = s2/6, vc = s2 - vrow*6;
  const u16* vsrc = Vp + (base + vrow)*48 + vc*8;
  int vkey = vrow ^ (vc<<3);           // swizzled key column (store side)
  if (t < 256){
    ux2 z = {0,0};
    *(ux2*)&Kl[0][(t>>2)*KSTRIDE + 48 + (t&3)*4] = z;
    *(ux2*)&Kl[1][(t>>2)*KSTRIDE + 48 + (t&3)*4] = z;
  }
  s16x8 qf[2][2];
  s16x8 zf = {0,0,0,0,0,0,0,0};
  #pragma unroll
  for (int n=0;n<2;n++){
    const u16* qrow = Qp + (base + q0 + n*16 + fr)*48;
    qf[n][0] = ld_bf8(qrow + fg*8);
    qf[n][1] = (fg < 2) ? ld_bf8(qrow + 32 + fg*8) : zf;
  }
  s16x8 ones;
  #pragma unroll
  for (int j=0;j<8;j++) ones[j] = (short)0x3F80;

  float m0r = -3.4e38f, m1r = -3.4e38f;
  fx4 o00=(fx4){0.f,0.f,0.f,0.f}, o01=o00, o02=o00, o03=o00, o10=o00, o11=o00, o12=o00, o13=o00;
  u16* pl = Pl[wv];
  ux4 kreg = {0,0,0,0}, vreg = {0,0,0,0};
  if (kact) kreg = *(const ux4*)ksrc;
  if (vact) vreg = *(const ux4*)vsrc;
  if (kact){
    ux2 lo; lo[0]=kreg[0]; lo[1]=kreg[1];
    ux2 hi; hi[0]=kreg[2]; hi[1]=kreg[3];
    *(ux2*)(Kl[0]+koff) = lo; *(ux2*)(Kl[0]+koff+4) = hi;
  }
  if (vact){
    u16* vcp = Vl[0] + vkey;
    vcp[(vc*8+0)*KSTRIDE] = (u16)vreg[0];
    vcp[(vc*8+1)*KSTRIDE] = (u16)(vreg[0]>>16);
    vcp[(vc*8+2)*KSTRIDE] = (u16)vreg[1];
    vcp[(vc*8+3)*KSTRIDE] = (u16)(vreg[1]>>16);
    vcp[(vc*8+4)*KSTRIDE] = (u16)vreg[2];
    vcp[(vc*8+5)*KSTRIDE] = (u16)(vreg[2]>>16);
    vcp[(vc*8+6)*KSTRIDE] = (u16)vreg[3];
    vcp[(vc*8+7)*KSTRIDE] = (u16)(vreg[3]>>16);
  }
  __syncthreads();

  for (int c=0;c<16;c++){
    int cur = c & 1;
    const u16* kl = Kl[cur];
    const u16* vl = Vl[cur];
    if (c < 15){
      if (kact) kreg = *(const ux4*)(ksrc + (size_t)(c+1)*3072);
      if (vact) vreg = *(const ux4*)(vsrc + (size_t)(c+1)*3072);
    }
    fx4 s0[4], s1v[4];
    __builtin_amdgcn_s_setprio(1);
    #pragma unroll
    for (int m=0;m<4;m++){
      s0[m]=(fx4){0.f,0.f,0.f,0.f}; s1v[m]=s0[m];
      #pragma unroll
      for (int s=0;s<2;s++){
        s16x8 af = ld_bf8(kl + (m*16+fr)*KSTRIDE + s*32 + fg*8);
        s0[m]  = __builtin_amdgcn_mfma_f32_16x16x32_bf16(af, qf[0][s], s0[m],  0,0,0);
        s1v[m] = __builtin_amdgcn_mfma_f32_16x16x32_bf16(af, qf[1][s], s1v[m], 0,0,0);
      }
    }
    __builtin_amdgcn_s_setprio(0);
    float pm0 = -3.4e38f, pm1 = -3.4e38f;
    #pragma unroll
    for (int m=0;m<4;m++){
      float a0 = fmaxf(fmaxf(s0[m][0],s0[m][1]), fmaxf(s0[m][2],s0[m][3]));
      float a1 = fmaxf(fmaxf(s1v[m][0],s1v[m][1]), fmaxf(s1v[m][2],s1v[m][3]));
      pm0 = fmaxf(pm0, a0); pm1 = fmaxf(pm1, a1);
    }
    pm0 = fmaxf(pm0, __shfl_xor(pm0,16)); pm0 = fmaxf(pm0, __shfl_xor(pm0,32));
    pm1 = fmaxf(pm1, __shfl_xor(pm1,16)); pm1 = fmaxf(pm1, __shfl_xor(pm1,32));
    if (!__all((pm0 <= m0r + DEFER_RAW) & (pm1 <= m1r + DEFER_RAW))){
      float nm0 = fmaxf(m0r, pm0), nm1 = fmaxf(m1r, pm1);
      float f0 = __builtin_amdgcn_exp2f((m0r - nm0)*E2SCALE);
      float f1 = __builtin_amdgcn_exp2f((m1r - nm1)*E2SCALE);
      m0r = nm0; m1r = nm1;
      #pragma unroll
      for (int j=0;j<4;j++){
        float g0 = __shfl(f0, fg*4+j);
        float g1 = __shfl(f1, fg*4+j);
        o00[j]*=g0; o01[j]*=g0; o02[j]*=g0; o03[j]*=g0;
        o10[j]*=g1; o11[j]*=g1; o12[j]*=g1; o13[j]*=g1;
      }
    }
    #pragma unroll
    for (int m=0;m<4;m++){
      float e0[4], e1[4];
      #pragma unroll
      for (int j=0;j<4;j++){
        e0[j] = __builtin_amdgcn_exp2f((s0[m][j]-m0r)*E2SCALE);
        e1[j] = __builtin_amdgcn_exp2f((s1v[m][j]-m1r)*E2SCALE);
      }
      ux2 P0, P1;
      P0[0]=cvtpk(e0[0],e0[1]); P0[1]=cvtpk(e0[2],e0[3]);
      P1[0]=cvtpk(e1[0],e1[1]); P1[1]=cvtpk(e1[2],e1[3]);
      *(ux2*)&pl[(fr)*KSTRIDE + m*16 + fg*4]      = P0;
      *(ux2*)&pl[(16+fr)*KSTRIDE + m*16 + fg*4]   = P1;
    }
    __builtin_amdgcn_s_setprio(1);
    #pragma unroll
    for (int s=0;s<2;s++){
      int kb = s*32 + fg*8;
      s16x8 pa0 = ld_bf8(pl + fr*KSTRIDE + kb);
      s16x8 pa1 = ld_bf8(pl + (16+fr)*KSTRIDE + kb);
      s16x8 vb0 = ld_bf8(vl + (fr)*KSTRIDE    + (kb ^ ((fr)&56)));
      s16x8 vb1 = ld_bf8(vl + (16+fr)*KSTRIDE + (kb ^ ((16+fr)&56)));
      s16x8 vb2 = ld_bf8(vl + (32+fr)*KSTRIDE + (kb ^ ((32+fr)&56)));
      o00 = __builtin_amdgcn_mfma_f32_16x16x32_bf16(pa0, vb0, o00, 0,0,0);
      o01 = __builtin_amdgcn_mfma_f32_16x16x32_bf16(pa0, vb1, o01, 0,0,0);
      o02 = __builtin_amdgcn_mfma_f32_16x16x32_bf16(pa0, vb2, o02, 0,0,0);
      o03 = __builtin_amdgcn_mfma_f32_16x16x32_bf16(pa0, ones, o03, 0,0,0);
      o10 = __builtin_amdgcn_mfma_f32_16x16x32_bf16(pa1, vb0, o10, 0,0,0);
      o11 = __builtin_amdgcn_mfma_f32_16x16x32_bf16(pa1, vb1, o11, 0,0,0);
      o12 = __builtin_amdgcn_mfma_f32_16x16x32_bf16(pa1, vb2, o12, 0,0,0);
      o13 = __builtin_amdgcn_mfma_f32_16x16x32_bf16(pa1, ones, o13, 0,0,0);
    }
    __builtin_amdgcn_s_setprio(0);
    if (c < 15){
      u16* kln = Kl[cur^1];
      u16* vln = Vl[cur^1];
      if (kact){
        ux2 lo; lo[0]=kreg[0]; lo[1]=kreg[1];
        ux2 hi; hi[0]=kreg[2]; hi[1]=kreg[3];
        *(ux2*)(kln+koff) = lo; *(ux2*)(kln+koff+4) = hi;
      }
      if (vact){
        u16* vcp = vln + vkey;
        vcp[(vc*8+0)*KSTRIDE] = (u16)vreg[0];
        vcp[(vc*8+1)*KSTRIDE] = (u16)(vreg[0]>>16);
        vcp[(vc*8+2)*KSTRIDE] = (u16)vreg[1];
        vcp[(vc*8+3)*KSTRIDE] = (u16)(vreg[1]>>16);
        vcp[(vc*8+4)*KSTRIDE] = (u16)vreg[2];
        vcp[(vc*8+5)*KSTRIDE] = (u16)(vreg[2]>>16);
        vcp[(vc*8+6)*KSTRIDE] = (u16)vreg[3];
        vcp[(vc*8+7)*KSTRIDE] = (u16)(vreg[3]>>16);
      }
      __syncthreads();
    }
  }
  const int* ord = order + w*1024 + q0;
  #pragma unroll
  for (int j=0;j<4;j++){
    float inv0 = 1.0f / o03[j];
    float inv1 = 1.0f / o13[j];
    int orig0 = ord[fg*4+j];
    u16* dst0 = attn + (size_t)orig0*384 + h*48;
    dst0[fr]      = f2bf(o00[j]*inv0);
    dst0[16+fr]   = f2bf(o01[j]*inv0);
    dst0[32+fr]   = f2bf(o02[j]*inv0);
    int orig1 = ord[16 + fg*4+j];
    u16* dst1 = attn + (size_t)orig1*384 + h*48;
    dst1[fr]      = f2bf(o10[j]*inv1);
    dst1[16+fr]   = f2bf(o11[j]*inv1);
    dst1[32+fr]   = f2bf(o12[j]*inv1);
  }
}

extern "C" void kernel_launch(void* const* d_in, const int* in_sizes, int n_in,
                              void* d_out, int out_size, void* d_ws, size_t ws_size,
                              hipStream_t stream)
{
  (void)n_in; (void)out_size; (void)ws_size;
  const float* x     = (const float*)d_in[0];
  const float* xyz   = (const float*)d_in[1];
  const float* ln1_g = (const float*)d_in[2];
  const float* ln1_b = (const float*)d_in[3];
  const float* qkv_w = (const float*)d_in[4];
  const float* qkv_b = (const float*)d_in[5];
  const float* proj_w= (const float*)d_in[6];
  const float* proj_b= (const float*)d_in[7];
  const float* ln2_g = (const float*)d_in[8];
  const float* ln2_b = (const float*)d_in[9];
  const float* ffn_w1= (const float*)d_in[10];
  const float* ffn_b1= (const float*)d_in[11];
  const float* ffn_w2= (const float*)d_in[12];
  const float* ffn_b2= (const float*)d_in[13];
  int N = in_sizes[0]/384;
  int nw = N/1024;
  char* wsp = (char*)d_ws;
  size_t off = 0;
  auto alloc = [&](size_t bytes)->char*{ char* p = wsp + off; off = (off + bytes + 255) & ~(size_t)255; return p; };
  int*  order   = (int*)alloc((size_t)N*4);
  int*  iorder  = (int*)alloc((size_t)N*4);
  int*  gridO   = (int*)alloc((size_t)N*12);
  float* minsW  = (float*)alloc((size_t)(N/256)*12);
  u64*  keysA   = (u64*)alloc((size_t)N*8);
  u64*  keysB   = (u64*)alloc((size_t)N*8);
  u16*  qkv_wT  = (u16*)alloc((size_t)1152*384*2);
  u16*  proj_wT = (u16*)alloc((size_t)384*384*2);
  u16*  w1T     = (u16*)alloc((size_t)1536*384*2);
  u16*  w2T     = (u16*)alloc((size_t)384*1536*2);
  // layout so that [xn | Qp | Kp | Vp] is one contiguous region = mid for the FFN
  u16*  xn      = (u16*)alloc((size_t)N*384*2);
  u16*  Qp      = (u16*)alloc((size_t)N*48*8*2);
  u16*  Kp      = (u16*)alloc((size_t)N*48*8*2);
  u16*  Vp      = (u16*)alloc((size_t)N*48*8*2);
  u16*  xn2     = (u16*)alloc((size_t)N*384*2);
  u16*  y1b     = (u16*)alloc((size_t)N*384*2);    // y1 bf16, (C, M) layout
  u16*  attn    = xn;     // xn dead after QKV gemm
  u16*  mid     = xn;     // [xn|Qp|Kp|Vp] = N*1536*2 bytes, all dead when FFN1 runs
  float* outF = (float*)d_out;

  // ---- parallel Z-order sort (atomic-free min; final merge emits order + iorder) ----
  min3_kernel<<<N/256, 256, 0, stream>>>(xyz, minsW, N);
  bsort_keys_kernel<<<N/2048, 1024, 0, stream>>>(xyz, minsW, keysA, gridO, N);
  merge_kernel<false><<<N/1024, 256, 0, stream>>>(keysA, keysB, order, iorder, 2048, N);
  merge_kernel<false><<<N/1024, 256, 0, stream>>>(keysB, keysA, order, iorder, 4096, N);
  merge_kernel<true><<<N/1024, 256, 0, stream>>>(keysA, keysB, order, iorder, 8192, N);

  wtrans4_kernel<<<1728, 256, 0, stream>>>(qkv_w, proj_w, ffn_w1, ffn_w2, qkv_wT, proj_wT, w1T, w2T);
  ln32_kernel<false><<<N/32, 256, 32*388*4, stream>>>(x, ln1_g, ln1_b, xn, N);
  // QKV GEMM with fused RoPE + sorted scatter (replaces qkvb round-trip + rope kernel)
  gemm256qkv_kernel<<<(N/256)*(1152/128), 512, 0, stream>>>(xn, qkv_wT, qkv_b, iorder, gridO, Qp, Kp, Vp, N, 384);
  attn7_kernel<<<8*nw*4, 512, 0, stream>>>(Qp, Kp, Vp, order, attn, N, nw);
  // proj: y1 bf16 (C,M) = x + (attn @ proj_w + b)^T
  gemm128x2_kernel<2><<<(N/128)*(384/128), 256, 0, stream>>>(attn, proj_wT, proj_b, y1b, nullptr, x, nullptr, N, 384, 384);
  // LN2 reads y1 bf16 (column layout)
  ln32_kernel<true><<<N/32, 256, 32*388*4, stream>>>(y1b, ln2_g, ln2_b, xn2, N);
  gemm256_kernel<1><<<(N/256)*(1536/128), 512, 0, stream>>>(xn2, w1T, ffn_b1, mid, N, 1536, 384);
  // FFN2: d_out f32 (C,M) = y1 + (mid @ w2 + b2)^T
  gemm128x2_kernel<3><<<(N/128)*(384/128), 256, 0, stream>>>(mid, w2T, ffn_b2, nullptr, outF, nullptr, y1b, N, 384, 1536);
}